// Round 6
// baseline (1239.375 us; speedup 1.0000x reference)
//
#include <hip/hip_runtime.h>
#include <stdint.h>

// Problem constants
#define BB   16
#define TT   4096
#define DIN  64
#define DOUT 64
#define HH   128
#define LCH  64   // chunk length
#define CCH  64   // number of chunks (LCH*CCH == TT)

// HARD-WON FACTS (rounds 0-4):
//  * d_out is 4,194,304 float32 (16 MB): the REAL PART of the complex output,
//    flat index (b*4096 + t)*64 + o.  Writing more than 16 MB -> abort.
//  * Scratch: prefer d_ws (if ws_size is big enough), else embed in d_out:
//    each block (c,b) owns out floats [(b*4096+c*64)*64, +4096) = 2048 complex;
//    S[c,b] at complex [0,128), E[c,b] at [128,256) of its own region;
//    M ping-pong (2 x 16384 complex) chunked 1024/region in regions (b=15,
//    c=32..63) at complex [256,1280).  Writers/readers ordered by kernel
//    sequence; pass-2 block (c,b) reads S first and overwrites its region last.

// ---------- bf16 pack helpers (RNE) ----------
__device__ __forceinline__ uint32_t f2bf(float f) {
  uint32_t x = __float_as_uint(f);
  return (x + 0x7FFFu + ((x >> 16) & 1u)) >> 16;
}
__device__ __forceinline__ uint32_t pack_bf(float re, float im) {
  return f2bf(re) | (f2bf(im) << 16);
}
__device__ __forceinline__ float bf_re(uint32_t u) { return __uint_as_float(u << 16); }
__device__ __forceinline__ float bf_im(uint32_t u) { return __uint_as_float(u & 0xFFFF0000u); }

// M-buffer indexer: chunked (embedded in d_out) or flat (d_ws)
__device__ __forceinline__ float2* mAt(float2* base, int e, int mch) {
  return mch ? (base + ((size_t)(e >> 10) * 2048 + (e & 1023))) : (base + e);
}

// ---------------------------------------------------------------------------
// Fused chunk-scan kernel.  One block = (chunk c, batch b), 256 threads.
//   phase 0: stage x chunk (bf16, LDS xt) + Wi (bf16, LDS wt)
//   phase 1: xp = x @ Wi^T into registers (4h x 8t tile / thread)
//   phase 2: write xp into LDS (overwriting Wi), init hbuf (0 or S[c,b])
//   phase 3: 64-step scan  h <- xp_t + i*(Wh @ h); Wh row-half in 128 VGPRs
//   EMIT=false: write chunk-end state to E[c,b].
//   EMIT=true: h overwrites xp slots, then phase 4: Re(h @ Wo^T) -> d_out.
// LDS: 17408 + 33792 + 1024 + 1024 = 53248 B
// ---------------------------------------------------------------------------
template <bool EMIT>
__global__ __launch_bounds__(256) void k_scan_fused(
    const float* __restrict__ xr, const float* __restrict__ xi,
    const float* __restrict__ wir, const float* __restrict__ wii,
    const float* __restrict__ whr, const float* __restrict__ whi,
    const float* __restrict__ wor, const float* __restrict__ woi,
    float2* __restrict__ Sb, int sb, int sc,
    float* __restrict__ out) {
  __shared__ __align__(16) unsigned char smem[53248];
  uint32_t* xt  = (uint32_t*)smem;             // [64][68]  x chunk [d][t]
  uint32_t* wt  = (uint32_t*)(smem + 17408);   // [64][132] Wi [d][h]
  uint32_t* xpl = (uint32_t*)(smem + 17408);   // [64][128] xp/h [t][h] (alias)
  uint32_t* woA = (uint32_t*)smem;             // [64][68]  Wo half (alias of xt)
  float2* hbuf = (float2*)(smem + 51200);      // state (fp32, exact)
  float2* part = (float2*)(smem + 52224);      // k-split partial sums
  const int tid = threadIdx.x;
  const int c = blockIdx.x >> 4;
  const int b = blockIdx.x & 15;
  float2* Sp = Sb + (size_t)b * sb + (size_t)c * sc;   // S at [0,128), E at [128,256)

  // ---- phase 0: stage x chunk + Wi (packed bf16) ----
  const size_t xbase = ((size_t)b * TT + (size_t)c * LCH) * DIN;
  for (int idx = tid; idx < LCH * DIN; idx += 256) {
    const int t = idx >> 6, d = idx & 63;
    xt[d * 68 + t] = pack_bf(xr[xbase + idx], xi[xbase + idx]);
  }
  for (int idx = tid; idx < HH * DIN; idx += 256) {
    const int h = idx >> 6, d = idx & 63;
    wt[d * 132 + h] = pack_bf(wir[idx], wii[idx]);
  }
  __syncthreads();

  // ---- phase 1: xp = x @ Wi^T  (thread tile: h = ho*4+a, t = tg*8+tt) ----
  const int ho = tid & 31;
  const int tg = tid >> 5;
  float accr[4][8], acci[4][8];
#pragma unroll
  for (int a = 0; a < 4; ++a)
#pragma unroll
    for (int t = 0; t < 8; ++t) { accr[a][t] = 0.f; acci[a][t] = 0.f; }
  for (int d = 0; d < DIN; ++d) {
    const uint4 wv  = *(const uint4*)&wt[d * 132 + ho * 4];
    const uint4 xv0 = *(const uint4*)&xt[d * 68 + tg * 8];
    const uint4 xv1 = *(const uint4*)&xt[d * 68 + tg * 8 + 4];
    float wre[4], wim[4], xre[8], xim[8];
    wre[0] = bf_re(wv.x); wim[0] = bf_im(wv.x);
    wre[1] = bf_re(wv.y); wim[1] = bf_im(wv.y);
    wre[2] = bf_re(wv.z); wim[2] = bf_im(wv.z);
    wre[3] = bf_re(wv.w); wim[3] = bf_im(wv.w);
    xre[0] = bf_re(xv0.x); xim[0] = bf_im(xv0.x);
    xre[1] = bf_re(xv0.y); xim[1] = bf_im(xv0.y);
    xre[2] = bf_re(xv0.z); xim[2] = bf_im(xv0.z);
    xre[3] = bf_re(xv0.w); xim[3] = bf_im(xv0.w);
    xre[4] = bf_re(xv1.x); xim[4] = bf_im(xv1.x);
    xre[5] = bf_re(xv1.y); xim[5] = bf_im(xv1.y);
    xre[6] = bf_re(xv1.z); xim[6] = bf_im(xv1.z);
    xre[7] = bf_re(xv1.w); xim[7] = bf_im(xv1.w);
#pragma unroll
    for (int a = 0; a < 4; ++a)
#pragma unroll
      for (int t = 0; t < 8; ++t) {
        accr[a][t] = fmaf(wre[a], xre[t], accr[a][t]);
        accr[a][t] = fmaf(-wim[a], xim[t], accr[a][t]);
        acci[a][t] = fmaf(wre[a], xim[t], acci[a][t]);
        acci[a][t] = fmaf(wim[a], xre[t], acci[a][t]);
      }
  }
  __syncthreads();   // all Wi reads done; wt region may be overwritten

  // ---- phase 2: write xp -> xpl [t][h], init hbuf ----
#pragma unroll
  for (int t = 0; t < 8; ++t) {
    uint4 v;
    v.x = pack_bf(accr[0][t], acci[0][t]);
    v.y = pack_bf(accr[1][t], acci[1][t]);
    v.z = pack_bf(accr[2][t], acci[2][t]);
    v.w = pack_bf(accr[3][t], acci[3][t]);
    *(uint4*)&xpl[(tg * 8 + t) * 128 + ho * 4] = v;
  }
  if (tid < HH) {
    hbuf[tid] = EMIT ? Sp[tid] : make_float2(0.f, 0.f);
  }

  // ---- load Wh row-half into registers ----
  const int j = tid & 127;
  const int p = tid >> 7;
  float wr[64], wi[64];
  {
    const float* pr = whr + (size_t)j * HH + p * 64;
    const float* pi = whi + (size_t)j * HH + p * 64;
#pragma unroll
    for (int kk = 0; kk < 64; kk += 4) {
      const float4 vr = *(const float4*)(pr + kk);
      wr[kk] = vr.x; wr[kk + 1] = vr.y; wr[kk + 2] = vr.z; wr[kk + 3] = vr.w;
      const float4 vi = *(const float4*)(pi + kk);
      wi[kk] = vi.x; wi[kk + 1] = vi.y; wi[kk + 2] = vi.z; wi[kk + 3] = vi.w;
    }
  }
  __syncthreads();

  // ---- phase 3: sequential scan over the chunk ----
#pragma unroll 1
  for (int s = 0; s < LCH; ++s) {
    float sre = 0.f, sim = 0.f;
#pragma unroll
    for (int kk = 0; kk < 64; ++kk) {
      const float2 hv = hbuf[p * 64 + kk];   // wave-uniform broadcast read
      sre = fmaf(wr[kk], hv.x, sre);
      sre = fmaf(-wi[kk], hv.y, sre);
      sim = fmaf(wr[kk], hv.y, sim);
      sim = fmaf(wi[kk], hv.x, sim);
    }
    if (p) part[j] = make_float2(sre, sim);
    __syncthreads();
    if (!p) {
      const float2 q = part[j];
      const uint32_t u = xpl[s * 128 + j];
      const float hr = bf_re(u) - (sim + q.y);   // re(xp) - Im(Wh h)
      const float hi = bf_im(u) + (sre + q.x);   // im(xp) + Re(Wh h)
      hbuf[j] = make_float2(hr, hi);
      if (EMIT) xpl[s * 128 + j] = pack_bf(hr, hi);  // h overwrites xp slot
    }
    __syncthreads();
  }

  if (!EMIT) {
    if (!p) Sp[128 + j] = hbuf[j];   // E[c,b]
    return;
  }

  // ---- phase 4: Re(h @ Wo^T) only.  thread tile: o = og*4+a, t = tg2*4+tt ----
  const int og = tid & 15;
  const int tg2 = tid >> 4;
  float orr[4][4];
#pragma unroll
  for (int a = 0; a < 4; ++a)
#pragma unroll
    for (int t = 0; t < 4; ++t) orr[a][t] = 0.f;
#pragma unroll 1
  for (int kp = 0; kp < 2; ++kp) {
    __syncthreads();   // prior woA readers done (xt region free after phase 1)
    for (int idx = tid; idx < DOUT * 64; idx += 256) {
      const int o = idx >> 6, hh = idx & 63;   // lanes sweep hh -> coalesced
      woA[hh * 68 + o] = pack_bf(wor[(size_t)o * HH + kp * 64 + hh],
                                 woi[(size_t)o * HH + kp * 64 + hh]);
    }
    __syncthreads();
    for (int hh = 0; hh < 64; ++hh) {
      const uint4 wv = *(const uint4*)&woA[hh * 68 + og * 4];
      float wre[4], wim[4];
      wre[0] = bf_re(wv.x); wim[0] = bf_im(wv.x);
      wre[1] = bf_re(wv.y); wim[1] = bf_im(wv.y);
      wre[2] = bf_re(wv.z); wim[2] = bf_im(wv.z);
      wre[3] = bf_re(wv.w); wim[3] = bf_im(wv.w);
#pragma unroll
      for (int tt = 0; tt < 4; ++tt) {
        const uint32_t hu = xpl[(tg2 * 4 + tt) * 128 + kp * 64 + hh];
        const float hre = bf_re(hu), him = bf_im(hu);
#pragma unroll
        for (int a = 0; a < 4; ++a) {
          orr[a][tt] = fmaf(wre[a], hre, orr[a][tt]);
          orr[a][tt] = fmaf(-wim[a], him, orr[a][tt]);
        }
      }
    }
  }
#pragma unroll
  for (int tt = 0; tt < 4; ++tt) {
    // real-only output: flat = (b*T + c*64 + t)*DOUT + o   (max 4,194,303)
    float* po = out + ((size_t)b * TT + (size_t)c * LCH + tg2 * 4 + tt) * DOUT + og * 4;
    *(float4*)po = make_float4(orr[0][tt], orr[1][tt], orr[2][tt], orr[3][tt]);
  }
}

// ---------------------------------------------------------------------------
// Complex matrix squaring  dst = A @ A  (128x128), fp32 exact.
// grid 64 = 8x8 tiles of 16x16, block 256.  fromPlanes=1: A = (ar,ai) planes
// (src still a valid pointer, never dereferenced OOB).
// ---------------------------------------------------------------------------
__global__ __launch_bounds__(256) void k_matsq(
    const float* __restrict__ ar, const float* __restrict__ ai,
    int fromPlanes, float2* __restrict__ src, float2* __restrict__ dst,
    int mch) {
  __shared__ float2 band[16 * HH];    // A[i-band][k]   16 KB
  __shared__ float2 panel[32 * HH];   // A[k-panel][j]  32 KB
  const int tid = threadIdx.x;
  const int ib = blockIdx.x >> 3, jb = blockIdx.x & 7;
  for (int idx = tid; idx < 16 * HH; idx += 256) {
    const int e = (ib * 16 + (idx >> 7)) * HH + (idx & 127);
    band[idx] = fromPlanes ? make_float2(ar[e], ai[e]) : *mAt(src, e, mch);
  }
  const int jt = tid & 15, it = tid >> 4;
  float sre = 0.f, sim = 0.f;
  for (int kp = 0; kp < 4; ++kp) {
    __syncthreads();   // covers band staging on first iteration
    for (int idx = tid; idx < 32 * HH; idx += 256) {
      const int e = (kp * 32 + (idx >> 7)) * HH + (idx & 127);
      panel[idx] = fromPlanes ? make_float2(ar[e], ai[e]) : *mAt(src, e, mch);
    }
    __syncthreads();
#pragma unroll 4
    for (int kk = 0; kk < 32; ++kk) {
      const float2 a = band[it * HH + kp * 32 + kk];
      const float2 bv = panel[kk * HH + jb * 16 + jt];
      sre = fmaf(a.x, bv.x, sre); sre = fmaf(-a.y, bv.y, sre);
      sim = fmaf(a.x, bv.y, sim); sim = fmaf(a.y, bv.x, sim);
    }
  }
  *mAt(dst, (ib * 16 + it) * HH + jb * 16 + jt, mch) = make_float2(sre, sim);
}

// ---------------------------------------------------------------------------
// Sequential chunk combine.  S_0 = 0;  S_{c+1} = M S_c + E_c.  (M = Wh^64)
// grid BB, block 256 (j, p=k-half), M row-half in VGPRs.  Writes all S_c.
// ---------------------------------------------------------------------------
__global__ __launch_bounds__(256) void k_combine(
    float2* __restrict__ Sb, int sb, int sc,
    float2* __restrict__ M1, int mch) {
  __shared__ float2 hbuf[HH];
  __shared__ float2 part[HH];
  const int tid = threadIdx.x;
  const int j = tid & 127;
  const int p = tid >> 7;
  const int b = blockIdx.x;
  float mr[64], mi[64];
#pragma unroll
  for (int kk = 0; kk < 64; ++kk) {
    const float2 v = *mAt(M1, j * HH + p * 64 + kk, mch);
    mr[kk] = v.x; mi[kk] = v.y;
  }
  if (tid < HH) hbuf[tid] = make_float2(0.f, 0.f);
  __syncthreads();
#pragma unroll 1
  for (int c = 0; c < CCH; ++c) {
    float2* Sp = Sb + (size_t)b * sb + (size_t)c * sc;
    if (!p) Sp[j] = hbuf[j];
    float sre = 0.f, sim = 0.f;
#pragma unroll
    for (int kk = 0; kk < 64; ++kk) {
      const float2 hv = hbuf[p * 64 + kk];
      sre = fmaf(mr[kk], hv.x, sre);
      sre = fmaf(-mi[kk], hv.y, sre);
      sim = fmaf(mr[kk], hv.y, sim);
      sim = fmaf(mi[kk], hv.x, sim);
    }
    if (p) part[j] = make_float2(sre, sim);
    __syncthreads();
    if (!p) {
      const float2 q = part[j];
      const float2 e = Sp[128 + j];        // E[c,b]
      hbuf[j] = make_float2(e.x + sre + q.x, e.y + sim + q.y);  // M=(iWh)^64
    }
    __syncthreads();
  }
}

// ---------------------------------------------------------------------------
extern "C" void kernel_launch(void* const* d_in, const int* in_sizes, int n_in,
                              void* d_out, int out_size, void* d_ws, size_t ws_size,
                              hipStream_t stream) {
  const float* xr  = (const float*)d_in[0];
  const float* xi  = (const float*)d_in[1];
  const float* wir = (const float*)d_in[2];
  const float* wii = (const float*)d_in[3];
  const float* whr = (const float*)d_in[4];
  const float* whi = (const float*)d_in[5];
  const float* wor = (const float*)d_in[6];
  const float* woi = (const float*)d_in[7];
  float* out = (float*)d_out;

  // scratch placement: d_ws if big enough, else embedded in d_out
  const size_t needWS = ((size_t)BB * CCH * 256 + 2 * 16384) * sizeof(float2); // 2.25 MB
  float2 *Sb, *M0, *M1;
  int sb, sc, mch;
  if (ws_size >= needWS) {
    Sb = (float2*)d_ws; sb = CCH * 256; sc = 256;      // [S(128)|E(128)] per (c,b)
    M0 = Sb + (size_t)BB * CCH * 256;
    M1 = M0 + 16384;
    mch = 0;
  } else {
    Sb = (float2*)d_out; sb = 131072; sc = 2048;       // region-embedded slots
    M0 = (float2*)d_out + 2031872;                     // (15*4096+32*64)*32 + 256
    M1 = (float2*)d_out + 2064640;                     // M0 + 16*2048
    mch = 1;
  }

  // M = Wh^64 via 6 squarings (fp32 exact); result in M1
  k_matsq<<<64, 256, 0, stream>>>(whr, whi, 1, M0, M0, mch);  // Wh^2  -> M0
  k_matsq<<<64, 256, 0, stream>>>(whr, whi, 0, M0, M1, mch);  // Wh^4  -> M1
  k_matsq<<<64, 256, 0, stream>>>(whr, whi, 0, M1, M0, mch);  // Wh^8  -> M0
  k_matsq<<<64, 256, 0, stream>>>(whr, whi, 0, M0, M1, mch);  // Wh^16 -> M1
  k_matsq<<<64, 256, 0, stream>>>(whr, whi, 0, M1, M0, mch);  // Wh^32 -> M0
  k_matsq<<<64, 256, 0, stream>>>(whr, whi, 0, M0, M1, mch);  // Wh^64 -> M1

  // pass 1: local chunk scans (zero init) -> E slots (xp computed in-block)
  k_scan_fused<false><<<CCH * BB, 256, 0, stream>>>(
      xr, xi, wir, wii, whr, whi, wor, woi, Sb, sb, sc, out);

  // sequential combine across chunks -> S slots
  k_combine<<<BB, 256, 0, stream>>>(Sb, sb, sc, M1, mch);

  // pass 2: re-run chunks seeded with S, fused real-part output projection
  k_scan_fused<true><<<CCH * BB, 256, 0, stream>>>(
      xr, xi, wir, wii, whr, whi, wor, woi, Sb, sb, sc, out);
}